// Round 1
// baseline (70.339 us; speedup 1.0000x reference)
//
#include <hip/hip_runtime.h>
#include <math.h>

// DRMM fused kernel for MI355X (gfx950)
// B=32, D=16, L=512, Q=8, E=128, NB=30
// grid = B*D = 512 blocks, 512 threads each.
// Per block (b,d): gather 512 doc-token embeddings, cosine sims vs 8 query
// vectors, 8x30 histogram in LDS, then fused MLP (30->128->64->32->1) with
// inference BN + tanh, gate-weighted sum -> out[b*16+d].

#define BN_INV 0.99950037468777346f  // np.float32(1/sqrt(1+1e-3))

__device__ __forceinline__ float shflx(float v, int m) {
    return __shfl_xor(v, m, 64);
}

// static select from an 8-register array (avoid runtime-indexed reg arrays -> scratch)
__device__ __forceinline__ float sel8(const float* v, int i) {
    float a0 = (i & 1) ? v[1] : v[0];
    float a1 = (i & 1) ? v[3] : v[2];
    float a2 = (i & 1) ? v[5] : v[4];
    float a3 = (i & 1) ? v[7] : v[6];
    float b0 = (i & 2) ? a1 : a0;
    float b1 = (i & 2) ? a3 : a2;
    return (i & 4) ? b1 : b0;
}

__global__ __launch_bounds__(512, 4)
void drmm_kernel(const int* __restrict__ doc,
                 const int* __restrict__ query,
                 const float* __restrict__ emb,
                 const float* __restrict__ idf,
                 const float* __restrict__ w_gate,
                 const float* __restrict__ g_in, const float* __restrict__ b_in,
                 const float* __restrict__ W0, const float* __restrict__ b0,
                 const float* __restrict__ g0, const float* __restrict__ be0,
                 const float* __restrict__ W1, const float* __restrict__ b1,
                 const float* __restrict__ g1, const float* __restrict__ be1,
                 const float* __restrict__ W2, const float* __restrict__ b2,
                 const float* __restrict__ g2, const float* __restrict__ be2,
                 const float* __restrict__ W3, const float* __restrict__ b3,
                 const float* __restrict__ g3, const float* __restrict__ be3,
                 float* __restrict__ out)
{
    __shared__ float hist[8][30];
    __shared__ float xrow[8][30];
    __shared__ float h1s[8][128];
    __shared__ float h2s[8][64];
    __shared__ float h3s[8][32];
    __shared__ float qn_s[8];
    __shared__ float gate_s[8];
    __shared__ float part[8];

    const int tid = threadIdx.x;
    const int bd  = blockIdx.x;       // b*16 + d
    const int b   = bd >> 4;

    if (tid < 240) ((float*)hist)[tid] = 0.0f;

    const int g   = tid >> 4;   // group 0..31 (16 lanes each)
    const int t16 = tid & 15;

    // Each lane holds its 8-float slice of all 8 query vectors (64 VGPRs).
    float qs[8][8];
#pragma unroll
    for (int q = 0; q < 8; ++q) {
        int qi = query[b * 8 + q];
        const float4* qr = (const float4*)(emb + (size_t)qi * 128 + t16 * 8);
        float4 x0 = qr[0], x1 = qr[1];
        qs[q][0] = x0.x; qs[q][1] = x0.y; qs[q][2] = x0.z; qs[q][3] = x0.w;
        qs[q][4] = x1.x; qs[q][5] = x1.y; qs[q][6] = x1.z; qs[q][7] = x1.w;
    }

    // Query norms: group g (g<8) reduces q=g across its 16 lanes.
    if (g < 8) {
        float p[8];
#pragma unroll
        for (int q = 0; q < 8; ++q) {
            float s = 0.f;
#pragma unroll
            for (int j = 0; j < 8; ++j) s += qs[q][j] * qs[q][j];
            p[q] = s;
        }
        float s = sel8(p, g);
        s += shflx(s, 1); s += shflx(s, 2); s += shflx(s, 4); s += shflx(s, 8);
        if (t16 == 0) qn_s[g] = sqrtf(s);
    }

    // Gate softmax (serial on one thread; 8 terms, trivial).
    if (tid == 511) {
        float z[8]; float m = -1e30f;
#pragma unroll
        for (int q = 0; q < 8; ++q) {
            int qi = query[b * 8 + q];
            z[q] = w_gate[q] * idf[qi];
            m = fmaxf(m, z[q]);
        }
        float ssum = 0.f;
#pragma unroll
        for (int q = 0; q < 8; ++q) { z[q] = expf(z[q] - m); ssum += z[q]; }
#pragma unroll
        for (int q = 0; q < 8; ++q) gate_s[q] = z[q] / ssum;
    }
    __syncthreads();

    const float qn_r = (t16 < 8) ? qn_s[t16] : 0.f;
    const int* docrow = doc + (size_t)bd * 512;

    // 512 tokens / 32 groups = 16 iterations.
#pragma unroll 1
    for (int it = 0; it < 16; ++it) {
        int tok = it * 32 + g;
        int idx = docrow[tok];
        const float4* r = (const float4*)(emb + (size_t)idx * 128 + t16 * 8);
        float4 x0 = r[0], x1 = r[1];
        float v[8] = {x0.x, x0.y, x0.z, x0.w, x1.x, x1.y, x1.z, x1.w};

        float dd = 0.f;
#pragma unroll
        for (int j = 0; j < 8; ++j) dd += v[j] * v[j];
        float dq[8];
#pragma unroll
        for (int q = 0; q < 8; ++q) {
            float s = 0.f;
#pragma unroll
            for (int j = 0; j < 8; ++j) s += v[j] * qs[q][j];
            dq[q] = s;
        }
        // butterfly reduce across the 16-lane group (9 values)
#pragma unroll
        for (int off = 8; off >= 1; off >>= 1) {
            dd += shflx(dd, off);
#pragma unroll
            for (int q = 0; q < 8; ++q) dq[q] += shflx(dq[q], off);
        }
        if (t16 < 8) {
            float dqq = sel8(dq, t16);
            float sim = dqq / (sqrtf(dd) * qn_r + 1e-8f);
            float u = (sim - 0.001f) / 0.999f * 30.0f;   // match ref op order
            int bin = (int)floorf(u);
            bin = bin < 0 ? 0 : (bin > 29 ? 29 : bin);
            atomicAdd(&hist[t16][bin], 1.0f);
        }
    }
    __syncthreads();

    // ---- MLP: wave wid handles q = wid ----
    const int wid  = tid >> 6;
    const int lane = tid & 63;

    if (tid < 240) {
        int q = tid / 30, k = tid % 30;
        xrow[q][k] = g_in[k] * (hist[q][k] * BN_INV) + b_in[k];
    }
    __syncthreads();

    // layer 1: 30 -> 128 (lane j computes outputs j and j+64)
    {
        float a0 = 0.f, a1 = 0.f;
#pragma unroll
        for (int k = 0; k < 30; ++k) {
            float xk = xrow[wid][k];
            a0 += xk * W0[k * 128 + lane];
            a1 += xk * W0[k * 128 + 64 + lane];
        }
        a0 += b0[lane]; a1 += b0[lane + 64];
        h1s[wid][lane]      = tanhf(g0[lane]      * (a0 * BN_INV) + be0[lane]);
        h1s[wid][lane + 64] = tanhf(g0[lane + 64] * (a1 * BN_INV) + be0[lane + 64]);
    }
    __syncthreads();

    // layer 2: 128 -> 64
    {
        float a = 0.f;
#pragma unroll 8
        for (int k = 0; k < 128; ++k) a += h1s[wid][k] * W1[k * 64 + lane];
        a += b1[lane];
        h2s[wid][lane] = tanhf(g1[lane] * (a * BN_INV) + be1[lane]);
    }
    __syncthreads();

    // layer 3: 64 -> 32
    if (lane < 32) {
        float a = 0.f;
#pragma unroll 8
        for (int k = 0; k < 64; ++k) a += h2s[wid][k] * W2[k * 32 + lane];
        a += b2[lane];
        h3s[wid][lane] = tanhf(g2[lane] * (a * BN_INV) + be2[lane]);
    }
    __syncthreads();

    // layer 4: 32 -> 1, gate weighting
    if (lane == 0) {
        float a = 0.f;
#pragma unroll
        for (int k = 0; k < 32; ++k) a += h3s[wid][k] * W3[k];
        a += b3[0];
        float y = tanhf(g3[0] * (a * BN_INV) + be3[0]);
        part[wid] = gate_s[wid] * y;
    }
    __syncthreads();

    if (tid == 0) {
        float s = 0.f;
#pragma unroll
        for (int q = 0; q < 8; ++q) s += part[q];
        out[bd] = s;
    }
}

extern "C" void kernel_launch(void* const* d_in, const int* in_sizes, int n_in,
                              void* d_out, int out_size, void* d_ws, size_t ws_size,
                              hipStream_t stream) {
    (void)in_sizes; (void)n_in; (void)out_size; (void)d_ws; (void)ws_size;
    const int*   doc    = (const int*)d_in[0];
    const int*   query  = (const int*)d_in[1];
    const float* emb    = (const float*)d_in[2];
    const float* idf    = (const float*)d_in[3];
    const float* w_gate = (const float*)d_in[4];
    const float* g_in   = (const float*)d_in[5];
    const float* b_in   = (const float*)d_in[6];
    const float* W0  = (const float*)d_in[7];
    const float* b0  = (const float*)d_in[8];
    const float* g0  = (const float*)d_in[9];
    const float* be0 = (const float*)d_in[10];
    const float* W1  = (const float*)d_in[11];
    const float* b1  = (const float*)d_in[12];
    const float* g1  = (const float*)d_in[13];
    const float* be1 = (const float*)d_in[14];
    const float* W2  = (const float*)d_in[15];
    const float* b2  = (const float*)d_in[16];
    const float* g2  = (const float*)d_in[17];
    const float* be2 = (const float*)d_in[18];
    const float* W3  = (const float*)d_in[19];
    const float* b3  = (const float*)d_in[20];
    const float* g3  = (const float*)d_in[21];
    const float* be3 = (const float*)d_in[22];

    drmm_kernel<<<dim3(32 * 16), dim3(512), 0, stream>>>(
        doc, query, emb, idf, w_gate, g_in, b_in,
        W0, b0, g0, be0, W1, b1, g1, be1,
        W2, b2, g2, be2, W3, b3, g3, be3,
        (float*)d_out);
}

// Round 2
// 69.131 us; speedup vs baseline: 1.0175x; 1.0175x over previous
//
#include <hip/hip_runtime.h>
#include <math.h>

// DRMM fused kernel for MI355X (gfx950) — round 2: software-pipelined gathers,
// wave-private histograms, parallel gate softmax.
// B=32, D=16, L=512, Q=8, E=128, NB=30
// grid = B*D = 512 blocks, 512 threads each.

#define BN_INV 0.99950037468777346f  // np.float32(1/sqrt(1+1e-3))

__device__ __forceinline__ float shflx(float v, int m) {
    return __shfl_xor(v, m, 64);
}

// static select from an 8-register array (avoid runtime-indexed reg arrays -> scratch)
__device__ __forceinline__ float sel8(const float* v, int i) {
    float a0 = (i & 1) ? v[1] : v[0];
    float a1 = (i & 1) ? v[3] : v[2];
    float a2 = (i & 1) ? v[5] : v[4];
    float a3 = (i & 1) ? v[7] : v[6];
    float b0 = (i & 2) ? a1 : a0;
    float b1 = (i & 2) ? a3 : a2;
    return (i & 4) ? b1 : b0;
}

__global__ __launch_bounds__(512, 4)
void drmm_kernel(const int* __restrict__ doc,
                 const int* __restrict__ query,
                 const float* __restrict__ emb,
                 const float* __restrict__ idf,
                 const float* __restrict__ w_gate,
                 const float* __restrict__ g_in, const float* __restrict__ b_in,
                 const float* __restrict__ W0, const float* __restrict__ b0,
                 const float* __restrict__ g0, const float* __restrict__ be0,
                 const float* __restrict__ W1, const float* __restrict__ b1,
                 const float* __restrict__ g1, const float* __restrict__ be1,
                 const float* __restrict__ W2, const float* __restrict__ b2,
                 const float* __restrict__ g2, const float* __restrict__ be2,
                 const float* __restrict__ W3, const float* __restrict__ b3,
                 const float* __restrict__ g3, const float* __restrict__ be3,
                 float* __restrict__ out)
{
    // wave-private histograms: [wave][q][bin], row stride 33 so different q
    // rows land on different banks (33*q+bin -> diagonal).
    __shared__ float histw[8][8][33];
    __shared__ float xrow[8][30];
    __shared__ float h1s[8][128];
    __shared__ float h2s[8][64];
    __shared__ float h3s[8][32];
    __shared__ float qn_s[8];
    __shared__ float gate_s[8];
    __shared__ float part[8];

    const int tid = threadIdx.x;
    const int bd  = blockIdx.x;       // b*16 + d
    const int b   = bd >> 4;
    const int g   = tid >> 4;         // 16-lane group 0..31
    const int t16 = tid & 15;
    const int wid = tid >> 6;         // wave 0..7
    const int lane = tid & 63;

    for (int i = tid; i < 8 * 8 * 33; i += 512) ((float*)histw)[i] = 0.0f;

    // Each lane holds its 8-float slice of all 8 query vectors (64 VGPRs).
    float qs[8][8];
#pragma unroll
    for (int q = 0; q < 8; ++q) {
        int qi = query[b * 8 + q];
        const float4* qr = (const float4*)((const char*)emb +
                            (unsigned)qi * 512u + (unsigned)(t16 * 32));
        float4 x0 = qr[0], x1 = qr[1];
        qs[q][0] = x0.x; qs[q][1] = x0.y; qs[q][2] = x0.z; qs[q][3] = x0.w;
        qs[q][4] = x1.x; qs[q][5] = x1.y; qs[q][6] = x1.z; qs[q][7] = x1.w;
    }

    // Query norms: group g (g<8) reduces q=g across its 16 lanes.
    if (g < 8) {
        float p[8];
#pragma unroll
        for (int q = 0; q < 8; ++q) {
            float s = 0.f;
#pragma unroll
            for (int j = 0; j < 8; ++j) s += qs[q][j] * qs[q][j];
            p[q] = s;
        }
        float s = sel8(p, g);
        s += shflx(s, 1); s += shflx(s, 2); s += shflx(s, 4); s += shflx(s, 8);
        if (t16 == 0) qn_s[g] = sqrtf(s);
    }

    // Gate softmax: 8 parallel lanes (56..63 of wave 7), shuffle-reduced.
    if (tid >= 504) {
        int q = tid - 504;
        float z = w_gate[q] * idf[query[b * 8 + q]];
        float m = z;
        m = fmaxf(m, shflx(m, 1)); m = fmaxf(m, shflx(m, 2)); m = fmaxf(m, shflx(m, 4));
        float e = expf(z - m);
        float s = e;
        s += shflx(s, 1); s += shflx(s, 2); s += shflx(s, 4);
        gate_s[q] = e / s;
    }
    __syncthreads();

    const float qn_r = (t16 < 8) ? qn_s[t16] : 0.f;
    const int* docrow = doc + (size_t)bd * 512;

    // ---- main gather loop: depth-3 software pipeline (prefetch it+2) ----
#define GATHER(D0, D1, IT) {                                                  \
        int _i = docrow[(IT) * 32 + g];                                       \
        const float4* _r = (const float4*)((const char*)emb +                 \
                            (unsigned)_i * 512u + (unsigned)(t16 * 32));      \
        D0 = _r[0]; D1 = _r[1];                                               \
    }

    float4 c0, c1, d0, d1;
    GATHER(c0, c1, 0);
    GATHER(d0, d1, 1);

#pragma unroll 2
    for (int it = 0; it < 16; ++it) {
        float4 e0 = make_float4(0.f, 0.f, 0.f, 0.f);
        float4 e1 = make_float4(0.f, 0.f, 0.f, 0.f);
        if (it < 14) GATHER(e0, e1, it + 2);

        float v[8] = {c0.x, c0.y, c0.z, c0.w, c1.x, c1.y, c1.z, c1.w};

        float dd = 0.f;
#pragma unroll
        for (int j = 0; j < 8; ++j) dd += v[j] * v[j];
        float dq[8];
#pragma unroll
        for (int q = 0; q < 8; ++q) {
            float s = 0.f;
#pragma unroll
            for (int j = 0; j < 8; ++j) s += v[j] * qs[q][j];
            dq[q] = s;
        }
        // butterfly reduce across the 16-lane group (9 values) — same order
        // as round 1 (absmax was 0.0; keep bit-identical)
#pragma unroll
        for (int off = 8; off >= 1; off >>= 1) {
            dd += shflx(dd, off);
#pragma unroll
            for (int q = 0; q < 8; ++q) dq[q] += shflx(dq[q], off);
        }
        if (t16 < 8) {
            float dqq = sel8(dq, t16);
            float sim = dqq / (sqrtf(dd) * qn_r + 1e-8f);
            float u = (sim - 0.001f) / 0.999f * 30.0f;   // match ref op order
            int bin = (int)floorf(u);
            bin = bin < 0 ? 0 : (bin > 29 ? 29 : bin);
            atomicAdd(&histw[wid][t16][bin], 1.0f);
        }
        c0 = d0; c1 = d1; d0 = e0; d1 = e1;
    }
#undef GATHER
    __syncthreads();

    // merge wave-private hists (exact: small-integer floats, order-free) + BN
    if (tid < 240) {
        int q = tid / 30, k = tid - q * 30;
        float s = histw[0][q][k] + histw[1][q][k] + histw[2][q][k] + histw[3][q][k]
                + histw[4][q][k] + histw[5][q][k] + histw[6][q][k] + histw[7][q][k];
        xrow[q][k] = g_in[k] * (s * BN_INV) + b_in[k];
    }
    __syncthreads();

    // ---- MLP: wave wid handles q = wid ----
    // layer 1: 30 -> 128 (lane j computes outputs j and j+64)
    {
        float a0 = 0.f, a1 = 0.f;
#pragma unroll
        for (int k = 0; k < 30; ++k) {
            float xk = xrow[wid][k];
            a0 += xk * W0[k * 128 + lane];
            a1 += xk * W0[k * 128 + 64 + lane];
        }
        a0 += b0[lane]; a1 += b0[lane + 64];
        h1s[wid][lane]      = tanhf(g0[lane]      * (a0 * BN_INV) + be0[lane]);
        h1s[wid][lane + 64] = tanhf(g0[lane + 64] * (a1 * BN_INV) + be0[lane + 64]);
    }
    __syncthreads();

    // layer 2: 128 -> 64
    {
        float a = 0.f;
#pragma unroll 8
        for (int k = 0; k < 128; ++k) a += h1s[wid][k] * W1[k * 64 + lane];
        a += b1[lane];
        h2s[wid][lane] = tanhf(g1[lane] * (a * BN_INV) + be1[lane]);
    }
    __syncthreads();

    // layer 3: 64 -> 32
    if (lane < 32) {
        float a = 0.f;
#pragma unroll 8
        for (int k = 0; k < 64; ++k) a += h2s[wid][k] * W2[k * 32 + lane];
        a += b2[lane];
        h3s[wid][lane] = tanhf(g2[lane] * (a * BN_INV) + be2[lane]);
    }
    __syncthreads();

    // layer 4: 32 -> 1, gate weighting
    if (lane == 0) {
        float a = 0.f;
#pragma unroll
        for (int k = 0; k < 32; ++k) a += h3s[wid][k] * W3[k];
        a += b3[0];
        float y = tanhf(g3[0] * (a * BN_INV) + be3[0]);
        part[wid] = gate_s[wid] * y;
    }
    __syncthreads();

    if (tid == 0) {
        float s = 0.f;
#pragma unroll
        for (int q = 0; q < 8; ++q) s += part[q];
        out[bd] = s;
    }
}

extern "C" void kernel_launch(void* const* d_in, const int* in_sizes, int n_in,
                              void* d_out, int out_size, void* d_ws, size_t ws_size,
                              hipStream_t stream) {
    (void)in_sizes; (void)n_in; (void)out_size; (void)d_ws; (void)ws_size;
    const int*   doc    = (const int*)d_in[0];
    const int*   query  = (const int*)d_in[1];
    const float* emb    = (const float*)d_in[2];
    const float* idf    = (const float*)d_in[3];
    const float* w_gate = (const float*)d_in[4];
    const float* g_in   = (const float*)d_in[5];
    const float* b_in   = (const float*)d_in[6];
    const float* W0  = (const float*)d_in[7];
    const float* b0  = (const float*)d_in[8];
    const float* g0  = (const float*)d_in[9];
    const float* be0 = (const float*)d_in[10];
    const float* W1  = (const float*)d_in[11];
    const float* b1  = (const float*)d_in[12];
    const float* g1  = (const float*)d_in[13];
    const float* be1 = (const float*)d_in[14];
    const float* W2  = (const float*)d_in[15];
    const float* b2  = (const float*)d_in[16];
    const float* g2  = (const float*)d_in[17];
    const float* be2 = (const float*)d_in[18];
    const float* W3  = (const float*)d_in[19];
    const float* b3  = (const float*)d_in[20];
    const float* g3  = (const float*)d_in[21];
    const float* be3 = (const float*)d_in[22];

    drmm_kernel<<<dim3(32 * 16), dim3(512), 0, stream>>>(
        doc, query, emb, idf, w_gate, g_in, b_in,
        W0, b0, g0, be0, W1, b1, g1, be1,
        W2, b2, g2, be2, W3, b3, g3, be3,
        (float*)d_out);
}